// Round 5
// baseline (59.288 us; speedup 1.0000x reference)
//
#include <hip/hip_runtime.h>

// Two-phase:
//  P1: pose[f] = init_c2w[f] @ [[R(r[f]), t[f]],[0,0,0,1]]  (N rows, into d_ws)
//  P2: out[m] = pose[frame_idx[m]]  -- 64B gather, 4 threads/matrix,
//      4 independent records per thread (MLP), nt stores + nt idx loads
//      (keep per-XCD L2 dedicated to the hot 6.4 MB pose table).
// r[0], t[0] treated as zero (reference does r.at[0].set(0)).

typedef float v4f __attribute__((ext_vector_type(4)));

__global__ __launch_bounds__(256) void pose_table_kernel(
    const float* __restrict__ r,
    const float* __restrict__ t,
    const float* __restrict__ init_c2w,
    float*       __restrict__ table,
    int N)
{
    int f = blockIdx.x * blockDim.x + threadIdx.x;
    if (f >= N) return;

    float x, y, z, tx, ty, tz;
    if (f == 0) {
        x = y = z = tx = ty = tz = 0.0f;
    } else {
        const float* rp = r + 3 * (size_t)f;
        const float* tp = t + 3 * (size_t)f;
        x = rp[0]; y = rp[1]; z = rp[2];
        tx = tp[0]; ty = tp[1]; tz = tp[2];
    }

    // Rodrigues: R = I + A*skew + B*skew^2
    float n2 = x * x + y * y + z * z;
    float n = sqrtf(n2) + 1e-15f;
    float s, c;
    sincosf(n, &s, &c);
    float A = s / n;
    float B = (1.0f - c) / (n * n);

    float xx = x * x, yy = y * y, zz = z * z;
    float xy = x * y, xz = x * z, yz = y * z;

    float R00 = 1.0f - B * (yy + zz);
    float R01 = -A * z + B * xy;
    float R02 =  A * y + B * xz;
    float R10 =  A * z + B * xy;
    float R11 = 1.0f - B * (xx + zz);
    float R12 = -A * x + B * yz;
    float R20 = -A * y + B * xz;
    float R21 =  A * x + B * yz;
    float R22 = 1.0f - B * (xx + yy);

    const v4f* ip = reinterpret_cast<const v4f*>(init_c2w + (size_t)f * 16);
    v4f* op = reinterpret_cast<v4f*>(table + (size_t)f * 16);

#pragma unroll
    for (int i = 0; i < 4; ++i) {
        v4f a = ip[i];
        v4f o;
        o.x = a.x * R00 + a.y * R10 + a.z * R20;
        o.y = a.x * R01 + a.y * R11 + a.z * R21;
        o.z = a.x * R02 + a.y * R12 + a.z * R22;
        o.w = a.x * tx  + a.y * ty  + a.z * tz + a.w;
        op[i] = o;
    }
}

// 4 threads per matrix; each thread handles FOUR independent records at
// g + k*Q (stores stay fully coalesced within each segment). idx loads and
// out stores are non-temporal; table loads use the caches.
__global__ __launch_bounds__(256) void gather_kernel(
    const v4f* __restrict__ table,   // N x 4 v4f
    const int* __restrict__ frame_idx,
    v4f*       __restrict__ out,     // M4 v4f records
    int M4,                          // = 4*M
    int Q)                           // = ceil(M4/4)
{
    int g = blockIdx.x * blockDim.x + threadIdx.x;
    if (g >= Q) return;

    int g0 = g;
    int g1 = g + Q;
    int g2 = g + 2 * Q;
    int g3 = g + 3 * Q;

    // Tail handling: M4 may not be divisible by 4; guard each segment.
    bool b1 = g1 < M4, b2 = g2 < M4, b3 = g3 < M4;

    int f0 = __builtin_nontemporal_load(&frame_idx[g0 >> 2]);
    int f1 = b1 ? __builtin_nontemporal_load(&frame_idx[g1 >> 2]) : 0;
    int f2 = b2 ? __builtin_nontemporal_load(&frame_idx[g2 >> 2]) : 0;
    int f3 = b3 ? __builtin_nontemporal_load(&frame_idx[g3 >> 2]) : 0;

    v4f v0 = table[(size_t)f0 * 4 + (g0 & 3)];
    v4f v1 = b1 ? table[(size_t)f1 * 4 + (g1 & 3)] : v4f{};
    v4f v2 = b2 ? table[(size_t)f2 * 4 + (g2 & 3)] : v4f{};
    v4f v3 = b3 ? table[(size_t)f3 * 4 + (g3 & 3)] : v4f{};

    __builtin_nontemporal_store(v0, &out[g0]);
    if (b1) __builtin_nontemporal_store(v1, &out[g1]);
    if (b2) __builtin_nontemporal_store(v2, &out[g2]);
    if (b3) __builtin_nontemporal_store(v3, &out[g3]);
}

// Fallback: fused single-pass if ws too small.
__global__ __launch_bounds__(256) void learnpose_fused_kernel(
    const float* __restrict__ r,
    const float* __restrict__ t,
    const float* __restrict__ init_c2w,
    const int*   __restrict__ frame_idx,
    float*       __restrict__ out,
    int M)
{
    int m = blockIdx.x * blockDim.x + threadIdx.x;
    if (m >= M) return;

    int f = frame_idx[m];
    float x, y, z, tx, ty, tz;
    if (f == 0) {
        x = y = z = tx = ty = tz = 0.0f;
    } else {
        const float* rp = r + 3 * (size_t)f;
        const float* tp = t + 3 * (size_t)f;
        x = rp[0]; y = rp[1]; z = rp[2];
        tx = tp[0]; ty = tp[1]; tz = tp[2];
    }
    float n2 = x * x + y * y + z * z;
    float n = sqrtf(n2) + 1e-15f;
    float s, c;
    sincosf(n, &s, &c);
    float A = s / n;
    float B = (1.0f - c) / (n * n);
    float xx = x * x, yy = y * y, zz = z * z;
    float xy = x * y, xz = x * z, yz = y * z;
    float R00 = 1.0f - B * (yy + zz);
    float R01 = -A * z + B * xy;
    float R02 =  A * y + B * xz;
    float R10 =  A * z + B * xy;
    float R11 = 1.0f - B * (xx + zz);
    float R12 = -A * x + B * yz;
    float R20 = -A * y + B * xz;
    float R21 =  A * x + B * yz;
    float R22 = 1.0f - B * (xx + yy);

    const v4f* ip = reinterpret_cast<const v4f*>(init_c2w + (size_t)f * 16);
    v4f* op = reinterpret_cast<v4f*>(out + (size_t)m * 16);
#pragma unroll
    for (int i = 0; i < 4; ++i) {
        v4f a = ip[i];
        v4f o;
        o.x = a.x * R00 + a.y * R10 + a.z * R20;
        o.y = a.x * R01 + a.y * R11 + a.z * R21;
        o.z = a.x * R02 + a.y * R12 + a.z * R22;
        o.w = a.x * tx  + a.y * ty  + a.z * tz + a.w;
        op[i] = o;
    }
}

extern "C" void kernel_launch(void* const* d_in, const int* in_sizes, int n_in,
                              void* d_out, int out_size, void* d_ws, size_t ws_size,
                              hipStream_t stream) {
    const float* r        = (const float*)d_in[0];
    const float* t        = (const float*)d_in[1];
    const float* init_c2w = (const float*)d_in[2];
    const int*   fidx     = (const int*)d_in[3];
    float* out = (float*)d_out;

    int N = in_sizes[0] / 3;
    int M = in_sizes[3];

    size_t table_bytes = (size_t)N * 16 * sizeof(float);
    if (ws_size >= table_bytes) {
        float* table = (float*)d_ws;
        int block = 256;
        int grid1 = (N + block - 1) / block;
        pose_table_kernel<<<grid1, block, 0, stream>>>(r, t, init_c2w, table, N);

        int M4 = 4 * M;
        int Q = (M4 + 3) / 4;
        int grid2 = (Q + block - 1) / block;
        gather_kernel<<<grid2, block, 0, stream>>>(
            (const v4f*)table, fidx, (v4f*)out, M4, Q);
    } else {
        int block = 256;
        int grid = (M + block - 1) / block;
        learnpose_fused_kernel<<<grid, block, 0, stream>>>(r, t, init_c2w, fidx, out, M);
    }
}

// Round 6
// 53.151 us; speedup vs baseline: 1.1155x; 1.1155x over previous
//
#include <hip/hip_runtime.h>

// Two-phase:
//  P1: pose[f] = init_c2w[f] @ [[R(r[f]), t[f]],[0,0,0,1]]  (N rows, into d_ws)
//  P2: out[g] = table[frame_idx[g>>2]*4 + (g&3)] -- 64B gather, 4 threads/rec,
//      persistent grid-stride loop (unroll 2) so idx-load / gather / store of
//      adjacent iterations overlap; NT stores keep L2 for the pose table.
// r[0], t[0] treated as zero (reference does r.at[0].set(0)).

typedef float v4f __attribute__((ext_vector_type(4)));

__global__ __launch_bounds__(256) void pose_table_kernel(
    const float* __restrict__ r,
    const float* __restrict__ t,
    const float* __restrict__ init_c2w,
    float*       __restrict__ table,
    int N)
{
    int f = blockIdx.x * blockDim.x + threadIdx.x;
    if (f >= N) return;

    float x, y, z, tx, ty, tz;
    if (f == 0) {
        x = y = z = tx = ty = tz = 0.0f;
    } else {
        const float* rp = r + 3 * (size_t)f;
        const float* tp = t + 3 * (size_t)f;
        x = rp[0]; y = rp[1]; z = rp[2];
        tx = tp[0]; ty = tp[1]; tz = tp[2];
    }

    // Rodrigues: R = I + A*skew + B*skew^2
    float n2 = x * x + y * y + z * z;
    float n = sqrtf(n2) + 1e-15f;
    float s, c;
    sincosf(n, &s, &c);
    float A = s / n;
    float B = (1.0f - c) / (n * n);

    float xx = x * x, yy = y * y, zz = z * z;
    float xy = x * y, xz = x * z, yz = y * z;

    float R00 = 1.0f - B * (yy + zz);
    float R01 = -A * z + B * xy;
    float R02 =  A * y + B * xz;
    float R10 =  A * z + B * xy;
    float R11 = 1.0f - B * (xx + zz);
    float R12 = -A * x + B * yz;
    float R20 = -A * y + B * xz;
    float R21 =  A * x + B * yz;
    float R22 = 1.0f - B * (xx + yy);

    const v4f* ip = reinterpret_cast<const v4f*>(init_c2w + (size_t)f * 16);
    v4f* op = reinterpret_cast<v4f*>(table + (size_t)f * 16);

#pragma unroll
    for (int i = 0; i < 4; ++i) {
        v4f a = ip[i];
        v4f o;
        o.x = a.x * R00 + a.y * R10 + a.z * R20;
        o.y = a.x * R01 + a.y * R11 + a.z * R21;
        o.z = a.x * R02 + a.y * R12 + a.z * R22;
        o.w = a.x * tx  + a.y * ty  + a.z * tz + a.w;
        op[i] = o;
    }
}

// Persistent grid-stride gather: 4 threads per 64B record.
__global__ __launch_bounds__(256) void gather_kernel(
    const v4f* __restrict__ table,   // N x 4 v4f
    const int* __restrict__ frame_idx,
    v4f*       __restrict__ out,     // M4 records
    int M4)                          // = 4*M
{
    int tid = blockIdx.x * blockDim.x + threadIdx.x;
    int stride = gridDim.x * blockDim.x;

    int iters = M4 / stride;         // full rounds every thread executes
    int g = tid;
#pragma unroll 2
    for (int i = 0; i < iters; ++i, g += stride) {
        int f = frame_idx[g >> 2];
        v4f v = table[(size_t)f * 4 + (g & 3)];
        __builtin_nontemporal_store(v, &out[g]);
    }
    if (g < M4) {
        int f = frame_idx[g >> 2];
        v4f v = table[(size_t)f * 4 + (g & 3)];
        __builtin_nontemporal_store(v, &out[g]);
    }
}

// Fallback: fused single-pass if ws too small.
__global__ __launch_bounds__(256) void learnpose_fused_kernel(
    const float* __restrict__ r,
    const float* __restrict__ t,
    const float* __restrict__ init_c2w,
    const int*   __restrict__ frame_idx,
    float*       __restrict__ out,
    int M)
{
    int m = blockIdx.x * blockDim.x + threadIdx.x;
    if (m >= M) return;

    int f = frame_idx[m];
    float x, y, z, tx, ty, tz;
    if (f == 0) {
        x = y = z = tx = ty = tz = 0.0f;
    } else {
        const float* rp = r + 3 * (size_t)f;
        const float* tp = t + 3 * (size_t)f;
        x = rp[0]; y = rp[1]; z = rp[2];
        tx = tp[0]; ty = tp[1]; tz = tp[2];
    }
    float n2 = x * x + y * y + z * z;
    float n = sqrtf(n2) + 1e-15f;
    float s, c;
    sincosf(n, &s, &c);
    float A = s / n;
    float B = (1.0f - c) / (n * n);
    float xx = x * x, yy = y * y, zz = z * z;
    float xy = x * y, xz = x * z, yz = y * z;
    float R00 = 1.0f - B * (yy + zz);
    float R01 = -A * z + B * xy;
    float R02 =  A * y + B * xz;
    float R10 =  A * z + B * xy;
    float R11 = 1.0f - B * (xx + zz);
    float R12 = -A * x + B * yz;
    float R20 = -A * y + B * xz;
    float R21 =  A * x + B * yz;
    float R22 = 1.0f - B * (xx + yy);

    const v4f* ip = reinterpret_cast<const v4f*>(init_c2w + (size_t)f * 16);
    v4f* op = reinterpret_cast<v4f*>(out + (size_t)m * 16);
#pragma unroll
    for (int i = 0; i < 4; ++i) {
        v4f a = ip[i];
        v4f o;
        o.x = a.x * R00 + a.y * R10 + a.z * R20;
        o.y = a.x * R01 + a.y * R11 + a.z * R21;
        o.z = a.x * R02 + a.y * R12 + a.z * R22;
        o.w = a.x * tx  + a.y * ty  + a.z * tz + a.w;
        op[i] = o;
    }
}

extern "C" void kernel_launch(void* const* d_in, const int* in_sizes, int n_in,
                              void* d_out, int out_size, void* d_ws, size_t ws_size,
                              hipStream_t stream) {
    const float* r        = (const float*)d_in[0];
    const float* t        = (const float*)d_in[1];
    const float* init_c2w = (const float*)d_in[2];
    const int*   fidx     = (const int*)d_in[3];
    float* out = (float*)d_out;

    int N = in_sizes[0] / 3;
    int M = in_sizes[3];

    size_t table_bytes = (size_t)N * 16 * sizeof(float);
    if (ws_size >= table_bytes) {
        float* table = (float*)d_ws;
        int block = 256;
        int grid1 = (N + block - 1) / block;
        pose_table_kernel<<<grid1, block, 0, stream>>>(r, t, init_c2w, table, N);

        int M4 = 4 * M;
        // Persistent-ish grid: 8 blocks/CU on 256 CUs = 2048 blocks,
        // capped so tiny problems still fill the machine.
        int grid2 = 2048;
        int maxg = (M4 + block - 1) / block;
        if (grid2 > maxg) grid2 = maxg;
        gather_kernel<<<grid2, block, 0, stream>>>(
            (const v4f*)table, fidx, (v4f*)out, M4);
    } else {
        int block = 256;
        int grid = (M + block - 1) / block;
        learnpose_fused_kernel<<<grid, block, 0, stream>>>(r, t, init_c2w, fidx, out, M);
    }
}